// Round 1
// 613.037 us; speedup vs baseline: 1.1894x; 1.1894x over previous
//
#include <hip/hip_runtime.h>

#define D_MODEL 2048
#define D_LATENT 512
#define NUM_HEADS 16
#define D_HEAD 128
#define BATCH 4
#define SEQ 2048
#define MTOK (BATCH*SEQ)   // 8192 tokens

typedef __bf16 bf16_t;
typedef __bf16 bf16x4 __attribute__((ext_vector_type(4)));
typedef __bf16 bf16x8 __attribute__((ext_vector_type(8)));
typedef float  f32x4  __attribute__((ext_vector_type(4)));

// async global->LDS, 16B per lane; LDS dst = wave-uniform base + lane*16 (m97 contract)
__device__ __forceinline__ void load_lds16(const bf16_t* g, bf16_t* l) {
  __builtin_amdgcn_global_load_lds(
      (const __attribute__((address_space(1))) void*)g,
      (__attribute__((address_space(3))) void*)l,
      16, 0, 0);
}

// ---------------- fp32 -> bf16 elementwise convert ----------------
__global__ void convert_f32_bf16_kernel(const float* __restrict__ src,
                                        bf16_t* __restrict__ dst, int n4) {
  int i = blockIdx.x * 256 + threadIdx.x;
  if (i >= n4) return;
  float4 v = *(const float4*)&src[(size_t)i * 4];
  bf16x4 o = { (bf16_t)v.x, (bf16_t)v.y, (bf16_t)v.z, (bf16_t)v.w };
  *(bf16x4*)&dst[(size_t)i * 4] = o;
}

// ------- weight transpose + convert: src f32 [R][C] -> dst bf16 [C][R] -------
__global__ void transpose_w_kernel(const float* __restrict__ src, bf16_t* __restrict__ dst,
                                   int R, int C) {
  __shared__ __align__(16) bf16_t tile[64][66];
  int rt = blockIdx.y * 64, ct = blockIdx.x * 64;
  int lc = threadIdx.x & 63, lr = threadIdx.x >> 6;
  for (int i = 0; i < 64; i += 4)
    tile[lr + i][lc] = (bf16_t)src[(size_t)(rt + lr + i) * C + ct + lc];
  __syncthreads();
  for (int i = 0; i < 64; i += 4)
    dst[(size_t)(ct + lr + i) * R + rt + lc] = tile[lc][lr + i];
}

// ------- V transpose: values bf16 [B*S][H*128] -> vt bf16 [B*H][128][S] -------
__global__ void transpose_v_kernel(const bf16_t* __restrict__ v, bf16_t* __restrict__ vt) {
  __shared__ __align__(16) bf16_t tile[64][66];
  int bh = blockIdx.z; int b = bh >> 4, h = bh & 15;
  int st = blockIdx.x * 64, dt = blockIdx.y * 64;
  int lc = threadIdx.x & 63, lr = threadIdx.x >> 6;
  const bf16_t* src = v + (size_t)b * SEQ * D_MODEL + h * D_HEAD;
  for (int i = 0; i < 64; i += 4)
    tile[lr + i][lc] = src[(size_t)(st + lr + i) * D_MODEL + dt + lc];
  __syncthreads();
  bf16_t* dst = vt + (size_t)bh * D_HEAD * SEQ;
  for (int i = 0; i < 64; i += 4)
    dst[(size_t)(dt + lr + i) * SEQ + st + lc] = tile[lc][lr + i];
}

// ---------------- GEMM: C[M][N] = (A[M][K] @ Wt[N][K]^T + bias[N]) * premul ----------------
// 128x128 tile, 4 waves, BK=32, global_load_lds width-16 staging (m97 structure).
// Swizzle: LDS chunk lc of row r holds global chunk lc ^ ((r>>1)&3).
template<typename OutT>
__global__ __launch_bounds__(256, 2) void gemm_bt_kernel(
    const bf16_t* __restrict__ A, const bf16_t* __restrict__ Wt,
    const float* __restrict__ bias, OutT* __restrict__ C,
    int M, int N, int K, float premul)
{
  __shared__ __align__(16) bf16_t As[128 * 32];
  __shared__ __align__(16) bf16_t Bs[128 * 32];
  int tid = threadIdx.x;
  int lane = tid & 63, wave = tid >> 6;
  int wr = (wave >> 1) * 64, wc = (wave & 1) * 64;
  size_t row0 = (size_t)blockIdx.x * 128, col0 = (size_t)blockIdx.y * 128;
  int lr = lane & 15, quad = lane >> 4, rq = quad * 4;

  f32x4 acc[4][4] = {};

  int srow = wave * 32 + (lane >> 2);
  int scol = ((lane & 3) ^ ((lane >> 3) & 3)) * 8;
  const bf16_t* Ag = A  + (row0 + srow) * K + scol;
  const bf16_t* Bg = Wt + (col0 + srow) * K + scol;
  bf16_t* Asw = As + wave * 1024;
  bf16_t* Bsw = Bs + wave * 1024;

  int rchunk = (quad ^ ((lr >> 1) & 3)) * 8;

  for (int k0 = 0; k0 < K; k0 += 32) {
    __syncthreads();
    load_lds16(Ag,          Asw);
    load_lds16(Ag + 16 * K, Asw + 512);
    load_lds16(Bg,          Bsw);
    load_lds16(Bg + 16 * K, Bsw + 512);
    Ag += 32; Bg += 32;
    __syncthreads();   // vmcnt(0) drained here -> LDS populated

    bf16x8 af[4], bfr[4];
    #pragma unroll
    for (int mi = 0; mi < 4; ++mi)
      af[mi] = *(const bf16x8*)&As[(wr + mi * 16 + lr) * 32 + rchunk];
    #pragma unroll
    for (int ni = 0; ni < 4; ++ni)
      bfr[ni] = *(const bf16x8*)&Bs[(wc + ni * 16 + lr) * 32 + rchunk];
    #pragma unroll
    for (int mi = 0; mi < 4; ++mi)
      #pragma unroll
      for (int ni = 0; ni < 4; ++ni)
        acc[mi][ni] = __builtin_amdgcn_mfma_f32_16x16x32_bf16(af[mi], bfr[ni], acc[mi][ni], 0, 0, 0);
  }

  // epilogue: C/D layout col=lane&15, row=quad*4+r  [m89-verified]
  #pragma unroll
  for (int ni = 0; ni < 4; ++ni) {
    int col = (int)col0 + wc + ni * 16 + lr;
    float bv = bias[col];
    #pragma unroll
    for (int mi = 0; mi < 4; ++mi) {
      #pragma unroll
      for (int r = 0; r < 4; ++r) {
        size_t row = row0 + wr + mi * 16 + rq + r;
        C[row * N + col] = (OutT)((acc[mi][ni][r] + bv) * premul);
      }
    }
  }
}

// ---------------- flash attention: one block per (b,h, 128 q rows) ----------------
// S^T orientation (q = lane&15); log2-domain softmax (Q pre-scaled in its GEMM).
// Ps aliases Ks -> LDS 36.9 KB.
// R6 changes vs R5-best:
//  - barrier after P-write removed: Ps rows [wave*32,wave*32+32) are written AND
//    read by the same wave only -> wave-local RAW through LDS, handled by lgkmcnt.
//    4 -> 3 __syncthreads per tile; PV overlaps other waves' softmax.
//  - T14 async-STAGE: next K/V tile global->reg loads issued right after the
//    post-QK^T barrier; latency hides under softmax+PV; the vmcnt(0) drain at
//    loop-top barrier finds data arrived. ds_write to LDS at loop top as before.
//  - T13 defer-max (THR=8, log2 domain): wave-uniform __all vote skips the
//    accO rescale + alpha shuffles when tile max didn't grow past m+8.
//  - T5 s_setprio(1) around QK^T and PV MFMA clusters.
__global__ __launch_bounds__(256, 2) void attention_kernel(
    const bf16_t* __restrict__ q, const bf16_t* __restrict__ keys,
    const bf16_t* __restrict__ vt, bf16_t* __restrict__ ctx)
{
  __shared__ __align__(16) bf16_t KP[128 * 72];  // union: Ks[64][136] / Ps[128][72]
  __shared__ __align__(16) bf16_t Vs[128][72];   // [d][key]
  bf16_t (*Ks)[136] = (bf16_t (*)[136])KP;
  bf16_t (*Ps)[72]  = (bf16_t (*)[72])KP;
  int bh = blockIdx.y; int b = bh >> 4, h = bh & 15;
  int qt = blockIdx.x;
  int tid = threadIdx.x, lane = tid & 63, wave = tid >> 6;
  int lr = lane & 15, quad = lane >> 4, kq = quad * 8, rq = quad * 4;

  const bf16_t* qg = q    + (size_t)(b * SEQ + qt * 128) * D_MODEL + h * D_HEAD;
  const bf16_t* kg = keys + (size_t)b * SEQ * D_MODEL + h * D_HEAD;
  const bf16_t* vg = vt   + (size_t)bh * D_HEAD * SEQ;

  // Q fragments (B operand; layout: n=lane&15, k=quad*8+j)
  bf16x8 qf[2][4];
  #pragma unroll
  for (int mi = 0; mi < 2; ++mi)
    #pragma unroll
    for (int ks = 0; ks < 4; ++ks)
      qf[mi][ks] = *(const bf16x8*)&qg[(size_t)(wave*32 + mi*16 + lr) * D_MODEL + ks*32 + kq];

  // staging coords + prefetch registers (T14)
  bf16x8 kreg[4], vreg[4];
  const bf16_t* kp4[4];
  const bf16_t* vp4[4];
  bf16_t* kd4[4];
  bf16_t* vd4[4];
  #pragma unroll
  for (int i = 0; i < 4; ++i) {
    int c = tid + i * 256;
    int r = c >> 4, kc = (c & 15) * 8;
    kp4[i] = kg + (size_t)r * D_MODEL + kc;
    kd4[i] = &Ks[r][kc];
    int d = c >> 3, vc = (c & 7) * 8;
    vp4[i] = vg + (size_t)d * SEQ + vc;
    vd4[i] = &Vs[d][vc];
  }
  #pragma unroll
  for (int i = 0; i < 4; ++i) {
    kreg[i] = *(const bf16x8*)kp4[i];
    vreg[i] = *(const bf16x8*)vp4[i];
  }

  f32x4 accO[2][8] = {};                  // O[q=base+rq+r][d=nd*16+lr]
  float m2[2]   = {-1e30f, -1e30f};       // running max (log2 domain), q = base+(lane&15)
  float lsum[2] = {0.f, 0.f};

  for (int kt = 0; kt < SEQ/64; ++kt) {
    __syncthreads();   // all waves done with prev tile's Ps/Vs reads; prefetch arrived
    #pragma unroll
    for (int i = 0; i < 4; ++i) {
      *(bf16x8*)kd4[i] = kreg[i];
      *(bf16x8*)vd4[i] = vreg[i];
    }
    __syncthreads();   // staging visible block-wide

    // S^T = K @ Q^T : sc[mi][ni][r] at key=ni*16+rq+r, q=wave*32+mi*16+lr
    f32x4 sc[2][4] = {};
    #pragma unroll
    for (int ks = 0; ks < 4; ++ks) {
      bf16x8 kf[4];
      #pragma unroll
      for (int ni = 0; ni < 4; ++ni) kf[ni] = *(const bf16x8*)&Ks[ni*16 + lr][ks*32 + kq];
      __builtin_amdgcn_s_setprio(1);
      #pragma unroll
      for (int mi = 0; mi < 2; ++mi)
        #pragma unroll
        for (int ni = 0; ni < 4; ++ni)
          sc[mi][ni] = __builtin_amdgcn_mfma_f32_16x16x32_bf16(kf[ni], qf[mi][ks], sc[mi][ni], 0, 0, 0);
      __builtin_amdgcn_s_setprio(0);
    }

    __syncthreads();   // all kf reads of Ks done before P overwrites it

    // T14: issue next tile's global loads now; they hide under softmax+PV and
    // the vmcnt(0) drain at the next loop-top barrier.
    if (kt + 1 < SEQ/64) {
      #pragma unroll
      for (int i = 0; i < 4; ++i) {
        kp4[i] += 64 * D_MODEL;
        vp4[i] += 64;
        kreg[i] = *(const bf16x8*)kp4[i];
        vreg[i] = *(const bf16x8*)vp4[i];
      }
    }

    // online softmax (log2 domain; scores already scaled by cs in the q-GEMM)
    #pragma unroll
    for (int mi = 0; mi < 2; ++mi) {
      float rm = sc[mi][0][0];
      #pragma unroll
      for (int ni = 0; ni < 4; ++ni)
        #pragma unroll
        for (int r = 0; r < 4; ++r) rm = fmaxf(rm, sc[mi][ni][r]);
      rm = fmaxf(rm, __shfl_xor(rm, 16, 64));
      rm = fmaxf(rm, __shfl_xor(rm, 32, 64));

      // T13 defer-max: skip rescale when the whole wave's rows grew < 2^8
      if (!__all(rm - m2[mi] <= 8.0f)) {
        float mnew  = fmaxf(m2[mi], rm);
        float alpha = exp2f(m2[mi] - mnew);
        m2[mi] = mnew;
        lsum[mi] *= alpha;
        float ar[4];
        #pragma unroll
        for (int r = 0; r < 4; ++r) ar[r] = __shfl(alpha, rq + r, 16);
        #pragma unroll
        for (int nd = 0; nd < 8; ++nd)
          #pragma unroll
          for (int r = 0; r < 4; ++r) accO[mi][nd][r] *= ar[r];
      }

      float rs = 0.f;
      int prow = wave*32 + mi*16 + lr;
      #pragma unroll
      for (int ni = 0; ni < 4; ++ni) {
        float p0 = exp2f(sc[mi][ni][0] - m2[mi]);
        float p1 = exp2f(sc[mi][ni][1] - m2[mi]);
        float p2 = exp2f(sc[mi][ni][2] - m2[mi]);
        float p3 = exp2f(sc[mi][ni][3] - m2[mi]);
        rs += (p0 + p1) + (p2 + p3);
        bf16x4 pk = { (bf16_t)p0, (bf16_t)p1, (bf16_t)p2, (bf16_t)p3 };
        *(bf16x4*)&Ps[prow][ni*16 + rq] = pk;   // 8B-aligned ds_write_b64
      }
      rs += __shfl_xor(rs, 16, 64);
      rs += __shfl_xor(rs, 32, 64);
      lsum[mi] += rs;
    }

    // NO barrier here: P rows [wave*32, wave*32+32) are wave-local (write+read
    // by the same wave); in-wave LDS RAW ordering handled by lgkmcnt.

    // O += P @ V   (A = P: m=q; B = V: n=d)
    #pragma unroll
    for (int ks2 = 0; ks2 < 2; ++ks2) {
      bf16x8 pf[2], vf[8];
      #pragma unroll
      for (int mi = 0; mi < 2; ++mi)
        pf[mi] = *(const bf16x8*)&Ps[wave*32 + mi*16 + lr][ks2*32 + kq];
      #pragma unroll
      for (int nd = 0; nd < 8; ++nd)
        vf[nd] = *(const bf16x8*)&Vs[nd*16 + lr][ks2*32 + kq];
      __builtin_amdgcn_s_setprio(1);
      #pragma unroll
      for (int mi = 0; mi < 2; ++mi)
        #pragma unroll
        for (int nd = 0; nd < 8; ++nd)
          accO[mi][nd] = __builtin_amdgcn_mfma_f32_16x16x32_bf16(pf[mi], vf[nd], accO[mi][nd], 0, 0, 0);
      __builtin_amdgcn_s_setprio(0);
    }
  }

  // finalize: ctx[token][h*128 + d]
  bf16_t* og = ctx + (size_t)(b * SEQ + qt * 128) * D_MODEL + h * D_HEAD;
  #pragma unroll
  for (int mi = 0; mi < 2; ++mi) {
    float inv[4];
    #pragma unroll
    for (int r = 0; r < 4; ++r) inv[r] = 1.0f / __shfl(lsum[mi], rq + r, 16);
    #pragma unroll
    for (int r = 0; r < 4; ++r) {
      int row = wave*32 + mi*16 + rq + r;
      #pragma unroll
      for (int nd = 0; nd < 8; ++nd)
        og[(size_t)row * D_MODEL + nd*16 + lr] = (bf16_t)(accO[mi][nd][r] * inv[r]);
    }
  }
}

extern "C" void kernel_launch(void* const* d_in, const int* in_sizes, int n_in,
                              void* d_out, int out_size, void* d_ws, size_t ws_size,
                              hipStream_t stream) {
  const float* x      = (const float*)d_in[0];
  const float* W_down = (const float*)d_in[1];
  const float* b_down = (const float*)d_in[2];
  const float* W_uk   = (const float*)d_in[3];
  const float* b_uk   = (const float*)d_in[4];
  const float* W_uv   = (const float*)d_in[5];
  const float* b_uv   = (const float*)d_in[6];
  const float* W_q    = (const float*)d_in[7];
  const float* b_q    = (const float*)d_in[8];
  const float* W_o    = (const float*)d_in[9];
  const float* b_o    = (const float*)d_in[10];
  float* out = (float*)d_out;

  char* ws = (char*)d_ws;
  bf16_t* xb      = (bf16_t*)ws;  ws += (size_t)MTOK*D_MODEL*2;
  bf16_t* Wt_down = (bf16_t*)ws;  ws += (size_t)D_LATENT*D_MODEL*2;
  bf16_t* Wt_uk   = (bf16_t*)ws;  ws += (size_t)D_MODEL*D_LATENT*2;
  bf16_t* Wt_uv   = (bf16_t*)ws;  ws += (size_t)D_MODEL*D_LATENT*2;
  bf16_t* Wt_q    = (bf16_t*)ws;  ws += (size_t)D_MODEL*D_MODEL*2;
  bf16_t* Wt_o    = (bf16_t*)ws;  ws += (size_t)D_MODEL*D_MODEL*2;
  bf16_t* lat     = (bf16_t*)ws;  ws += (size_t)MTOK*D_LATENT*2;
  bf16_t* keys    = (bf16_t*)ws;  ws += (size_t)MTOK*D_MODEL*2;
  bf16_t* vals    = (bf16_t*)ws;  ws += (size_t)MTOK*D_MODEL*2;
  bf16_t* qm      = (bf16_t*)ws;  ws += (size_t)MTOK*D_MODEL*2;
  bf16_t* vtm     = (bf16_t*)ws;  ws += (size_t)MTOK*D_MODEL*2;
  bf16_t* ctx     = vals;  // vals dead after transpose_v

  const float cs = 0.0883883476483184f * 1.44269504089f;  // 1/sqrt(128) * log2(e)

  convert_f32_bf16_kernel<<<(MTOK*D_MODEL/4 + 255)/256, 256, 0, stream>>>(x, xb, MTOK*D_MODEL/4);

  transpose_w_kernel<<<dim3(D_LATENT/64, D_MODEL/64), 256, 0, stream>>>(W_down, Wt_down, D_MODEL, D_LATENT);
  transpose_w_kernel<<<dim3(D_MODEL/64, D_LATENT/64), 256, 0, stream>>>(W_uk,   Wt_uk,   D_LATENT, D_MODEL);
  transpose_w_kernel<<<dim3(D_MODEL/64, D_LATENT/64), 256, 0, stream>>>(W_uv,   Wt_uv,   D_LATENT, D_MODEL);
  transpose_w_kernel<<<dim3(D_MODEL/64, D_MODEL/64),  256, 0, stream>>>(W_q,    Wt_q,    D_MODEL,  D_MODEL);
  transpose_w_kernel<<<dim3(D_MODEL/64, D_MODEL/64),  256, 0, stream>>>(W_o,    Wt_o,    D_MODEL,  D_MODEL);

  gemm_bt_kernel<bf16_t><<<dim3(MTOK/128, D_LATENT/128), 256, 0, stream>>>(xb,  Wt_down, b_down, lat,  MTOK, D_LATENT, D_MODEL, 1.0f);
  gemm_bt_kernel<bf16_t><<<dim3(MTOK/128, D_MODEL/128),  256, 0, stream>>>(lat, Wt_uk,   b_uk,   keys, MTOK, D_MODEL,  D_LATENT, 1.0f);
  gemm_bt_kernel<bf16_t><<<dim3(MTOK/128, D_MODEL/128),  256, 0, stream>>>(lat, Wt_uv,   b_uv,   vals, MTOK, D_MODEL,  D_LATENT, 1.0f);
  gemm_bt_kernel<bf16_t><<<dim3(MTOK/128, D_MODEL/128),  256, 0, stream>>>(xb,  Wt_q,    b_q,    qm,   MTOK, D_MODEL,  D_MODEL, cs);

  transpose_v_kernel<<<dim3(SEQ/64, D_HEAD/64, BATCH*NUM_HEADS), 256, 0, stream>>>(vals, vtm);

  attention_kernel<<<dim3(SEQ/128, BATCH*NUM_HEADS), 256, 0, stream>>>(qm, keys, vtm, ctx);

  gemm_bt_kernel<float><<<dim3(MTOK/128, D_MODEL/128), 256, 0, stream>>>(ctx, Wt_o, b_o, out, MTOK, D_MODEL, D_MODEL, 1.0f);
}